// Round 10
// baseline (123.184 us; speedup 1.0000x reference)
//
#include <hip/hip_runtime.h>

typedef __attribute__((ext_vector_type(4))) float f32x4;
typedef __attribute__((ext_vector_type(16))) float f32x16;
typedef __attribute__((ext_vector_type(8))) __bf16 bf16x8;
typedef __attribute__((ext_vector_type(4))) __bf16 bf16x4;
typedef __attribute__((ext_vector_type(4))) unsigned u32x4;
typedef __attribute__((ext_vector_type(2))) unsigned u32x2;

static __device__ __forceinline__ f32x4 mfma16(bf16x8 a, bf16x8 b, f32x4 c) {
    return __builtin_amdgcn_mfma_f32_16x16x32_bf16(a, b, c, 0, 0, 0);
}
static __device__ __forceinline__ f32x16 mfma32(bf16x8 a, bf16x8 b, f32x16 c) {
    return __builtin_amdgcn_mfma_f32_32x32x16_bf16(a, b, c, 0, 0, 0);
}
static __device__ __forceinline__ unsigned pk_bf16(float a, float b) {
    unsigned lo = __builtin_bit_cast(unsigned short, (__bf16)a);
    unsigned hh = __builtin_bit_cast(unsigned short, (__bf16)b);
    return lo | (hh << 16);
}

// Q pre-scale: 1/sqrt(64) * log2(e)  (exp2 applied directly to S, shift-free)
#define QSCALE 0.18033688f

// ---------------------------------------------------------------------------
// 1) fused prep: x cvt -> bf16 (blocks 0..4095), w_qkv transpose
//    (4096..7167), w_out transpose (7168..8191)
// ---------------------------------------------------------------------------
__global__ __launch_bounds__(256) void prep_all(const float* __restrict__ x,
                                                __bf16* __restrict__ xb,
                                                const float* __restrict__ wq,
                                                __bf16* __restrict__ wqT,
                                                const float* __restrict__ wo,
                                                __bf16* __restrict__ woT) {
    __shared__ float t[32][33];
    int bid = blockIdx.x, tid = threadIdx.x;
    if (bid < 4096) {
        int i = bid * 256 + tid;
        f32x4 v = ((const f32x4*)x)[i];
        bf16x4 o;
#pragma unroll
        for (int j = 0; j < 4; j++) o[j] = (__bf16)v[j];
        ((bf16x4*)xb)[i] = o;
        return;
    }
    const float* in;
    __bf16* out;
    int R, C, bx, by;
    if (bid < 4096 + 3072) {
        int b2 = bid - 4096;
        in = wq; out = wqT; R = 1024; C = 3072;
        bx = (b2 % 96) * 32; by = (b2 / 96) * 32;
    } else {
        int b2 = bid - 7168;
        in = wo; out = woT; R = 1024; C = 1024;
        bx = (b2 % 32) * 32; by = (b2 / 32) * 32;
    }
    int tx = tid & 31, ty = tid >> 5;  // 32 x 8
#pragma unroll
    for (int k = 0; k < 32; k += 8)
        t[ty + k][tx] = in[(size_t)(by + ty + k) * C + bx + tx];
    __syncthreads();
#pragma unroll
    for (int k = 0; k < 32; k += 8)
        out[(size_t)(bx + ty + k) * R + by + tx] = (__bf16)t[tx][ty + k];
}

// ---------------------------------------------------------------------------
// 3) bf16 GEMM (round-5 proven): orientation-B, 128x128 tile, BK=64, 4 waves,
//    single-buffer 2-barrier K-loop. MODE 0: fp32 float4 stores.
//    MODE 1: scatter QKV fragments (Q scaled; Qf/Kf bf16x4, Vf scalar).
// ---------------------------------------------------------------------------
#define BM 128
#define BN 128
#define BKG 64

template <int MODE>
__global__ __launch_bounds__(256) void gemm_bt(const __bf16* __restrict__ A,
                                               const __bf16* __restrict__ Bt,
                                               int M, int N, int K,
                                               float* __restrict__ Cout,
                                               __bf16* __restrict__ Qf,
                                               __bf16* __restrict__ Kf,
                                               __bf16* __restrict__ Vf) {
    __shared__ __attribute__((aligned(16))) __bf16 As[BM * BKG];
    __shared__ __attribute__((aligned(16))) __bf16 Bs[BN * BKG];
    int tid = threadIdx.x;
    int wave = tid >> 6, lane = tid & 63;
    int lrow = lane & 15, lgrp = lane >> 4;
    int chunk = gridDim.x >> 3;
    int bid = blockIdx.x;
    int swz = (bid & 7) * chunk + (bid >> 3);
    int nbx = N >> 7;
    int m0 = (swz / nbx) * BM, n0 = (swz % nbx) * BN;
    int wm = (wave >> 1) * 64, wn = (wave & 1) * 64;

    f32x4 acc[4][4];
#pragma unroll
    for (int i = 0; i < 4; i++)
#pragma unroll
        for (int j = 0; j < 4; j++) acc[i][j] = (f32x4){0.f, 0.f, 0.f, 0.f};

    int srow = tid >> 3;
    int gch = (tid & 7) ^ (srow & 7);
    const __bf16* aSrc = A + (size_t)(m0 + srow) * K + gch * 8;
    const __bf16* bSrc = Bt + (size_t)(n0 + srow) * K + gch * 8;

    for (int k0 = 0; k0 < K; k0 += BKG) {
#pragma unroll
        for (int c = 0; c < 4; c++) {
            __builtin_amdgcn_global_load_lds(
                (const __attribute__((address_space(1))) void*)(aSrc + k0 + (size_t)c * 32 * K),
                (__attribute__((address_space(3))) void*)(As + (c * 256 + wave * 64) * 8),
                16, 0, 0);
        }
#pragma unroll
        for (int c = 0; c < 4; c++) {
            __builtin_amdgcn_global_load_lds(
                (const __attribute__((address_space(1))) void*)(bSrc + k0 + (size_t)c * 32 * K),
                (__attribute__((address_space(3))) void*)(Bs + (c * 256 + wave * 64) * 8),
                16, 0, 0);
        }
        __syncthreads();
#pragma unroll
        for (int kk = 0; kk < 2; kk++) {
            bf16x8 af[4], bfr[4];
#pragma unroll
            for (int mt = 0; mt < 4; mt++) {
                int row = wm + mt * 16 + lrow;
                int slot = row * 8 + ((4 * kk + lgrp) ^ (row & 7));
                af[mt] = *(const bf16x8*)(As + slot * 8);
            }
#pragma unroll
            for (int nt = 0; nt < 4; nt++) {
                int row = wn + nt * 16 + lrow;
                int slot = row * 8 + ((4 * kk + lgrp) ^ (row & 7));
                bfr[nt] = *(const bf16x8*)(Bs + slot * 8);
            }
#pragma unroll
            for (int mt = 0; mt < 4; mt++)
#pragma unroll
                for (int nt = 0; nt < 4; nt++)
                    acc[mt][nt] = mfma16(af[mt], bfr[nt], acc[mt][nt]);
        }
        __syncthreads();
    }

#pragma unroll
    for (int mt = 0; mt < 4; mt++) {
#pragma unroll
        for (int nt = 0; nt < 4; nt++) {
            int f0 = m0 + wm + mt * 16 + lgrp * 4;
            int t = n0 + wn + nt * 16 + lrow;
            if (MODE == 0) {
                *(f32x4*)(Cout + (size_t)t * M + f0) = acc[mt][nt];
            } else {
                int which = f0 >> 10, hn = f0 & 1023;
                int h = hn >> 6, d0 = hn & 63;
                int b = t >> 11, li = t & 2047;
                int bh = b * 16 + h, c = li >> 5, tl = li & 31;
                size_t bhbase = (size_t)bh * 131072;
                if (which == 2) {
                    int ks = tl >> 4, hv = (tl >> 3) & 1, jv = tl & 7;
                    size_t base =
                        bhbase + ((size_t)(c * 4 + ks * 2 + hv) * 64 + d0) * 8 + jv;
#pragma unroll
                    for (int r = 0; r < 4; r++)
                        Vf[base + (size_t)r * 8] = (__bf16)acc[mt][nt][r];
                } else {
                    int st = d0 >> 4, hv = (d0 >> 3) & 1, j0 = d0 & 7;
                    size_t idx =
                        bhbase + ((size_t)(c * 8 + st * 2 + hv) * 32 + tl) * 8 + j0;
                    bf16x4 pv;
                    if (which == 0) {
#pragma unroll
                        for (int r = 0; r < 4; r++)
                            pv[r] = (__bf16)(acc[mt][nt][r] * QSCALE);
                        *(bf16x4*)(Qf + idx) = pv;
                    } else {
#pragma unroll
                        for (int r = 0; r < 4; r++) pv[r] = (__bf16)acc[mt][nt][r];
                        *(bf16x4*)(Kf + idx) = pv;
                    }
                }
            }
        }
    }
}

// ---------------------------------------------------------------------------
// 4) Causal flash attention v9: LDS-shared K/V, no combine.
//    Block = 128 q-rows = 4 waves; wave w owns strip S = tile*4 + w fully
//    (complete softmax + PV, direct write). The block's K-loop stages each
//    8KB K/V chunk ONCE into LDS (global_load_lds, double-buffered 16KB);
//    all 4 waves consume it via linear conflict-free ds_read_b128.
//    L2 traffic /4 vs per-wave loads; staging hidden under compute.
//    512 blocks = 8 xcd-groups x 4 bh x 16 tiles (heavy tile first).
// ---------------------------------------------------------------------------
__global__ __launch_bounds__(256) void attn_fwd9(const __bf16* __restrict__ Qf,
                                                 const __bf16* __restrict__ Kf,
                                                 const __bf16* __restrict__ Vf,
                                                 __bf16* __restrict__ Ob) {
    __shared__ __attribute__((aligned(16))) __bf16 kv[2][4096];  // [K 4KB | V 4KB]
    int tid = threadIdx.x;
    int wave = tid >> 6, lane = tid & 63;
    int ql = lane & 31, hi = lane >> 5;
    int bid = blockIdx.x;
    int xcd = bid & 7, idx = bid >> 3;      // 512 blocks: 8 x 64
    int bh = xcd * 4 + (idx >> 4);
    int tile = 15 - (idx & 15);             // heavy tiles first
    int S = tile * 4 + wave;                // this wave's strip
    int q0 = S * 32;
    int cmax = tile * 4 + 3;                // block K-loop bound

    const __bf16* Qp = Qf + (size_t)bh * 131072;
    const __bf16* Kp = Kf + (size_t)bh * 131072;
    const __bf16* Vp = Vf + (size_t)bh * 131072;

    // Q fragments for this wave's strip
    const __bf16* qb = Qp + ((size_t)S * 8 + hi) * 256 + ql * 8;
    bf16x8 qf[4];
#pragma unroll
    for (int st = 0; st < 4; st++) qf[st] = *(const bf16x8*)(qb + st * 512);

    f32x16 o0, o1;
#pragma unroll
    for (int r = 0; r < 16; r++) { o0[r] = 0.f; o1[r] = 0.f; }
    float ls = 0.f;

    // stage chunk c into buffer b: wave w copies its quarter of K and V
    // (fragment layouts are chunk-contiguous: Kf chunk c = Kp[c*2048..],
    //  Vf chunk c = Vp[c*2048..], 4KB each)
    auto STAGE = [&](int c, int b) {
        const __bf16* sK = Kp + (size_t)c * 2048 + wave * 512 + lane * 8;
        const __bf16* sV = Vp + (size_t)c * 2048 + wave * 512 + lane * 8;
        __builtin_amdgcn_global_load_lds(
            (const __attribute__((address_space(1))) void*)sK,
            (__attribute__((address_space(3))) void*)(&kv[b][wave * 512]), 16, 0, 0);
        __builtin_amdgcn_global_load_lds(
            (const __attribute__((address_space(1))) void*)sV,
            (__attribute__((address_space(3))) void*)(&kv[b][2048 + wave * 512]), 16, 0, 0);
    };

    auto COMPUTE = [&](int b, bool masked) {
        const __bf16* kb = &kv[b][hi * 256 + ql * 8];
        bf16x8 kf[4];
#pragma unroll
        for (int st = 0; st < 4; st++) kf[st] = *(const bf16x8*)(kb + st * 512);
        const __bf16* vb = &kv[b][2048 + hi * 512 + ql * 8];
        bf16x8 v00 = *(const bf16x8*)(vb);
        bf16x8 v01 = *(const bf16x8*)(vb + 256);
        bf16x8 v10 = *(const bf16x8*)(vb + 1024);
        bf16x8 v11 = *(const bf16x8*)(vb + 1280);

        f32x16 sa;
#pragma unroll
        for (int r = 0; r < 16; r++) sa[r] = 0.f;
#pragma unroll
        for (int st = 0; st < 4; st++) sa = mfma32(kf[st], qf[st], sa);

        float p[16];
        float psum = 0.f;
#pragma unroll
        for (int r = 0; r < 16; r++) {
            float s = sa[r];
            if (masked) {
                int krel = (r & 3) + 8 * (r >> 2) + 4 * hi;
                if (krel > ql) s = -1e30f;
            }
            float pv = __builtin_amdgcn_exp2f(s);
            p[r] = pv;
            psum += pv;
        }
        u32x2 ps = __builtin_amdgcn_permlane32_swap(
            __builtin_bit_cast(unsigned, psum), __builtin_bit_cast(unsigned, psum),
            false, false);
        psum += __builtin_bit_cast(float, hi ? ps[0] : ps[1]);
        ls += psum;

        unsigned w[8];
#pragma unroll
        for (int i = 0; i < 8; i++) w[i] = pk_bf16(p[2 * i], p[2 * i + 1]);
        u32x2 r02 = __builtin_amdgcn_permlane32_swap(w[0], w[2], false, false);
        u32x2 r13 = __builtin_amdgcn_permlane32_swap(w[1], w[3], false, false);
        u32x2 r46 = __builtin_amdgcn_permlane32_swap(w[4], w[6], false, false);
        u32x2 r57 = __builtin_amdgcn_permlane32_swap(w[5], w[7], false, false);
        bf16x8 pa0 = __builtin_bit_cast(bf16x8, (u32x4){r02[0], r13[0], r02[1], r13[1]});
        bf16x8 pa1 = __builtin_bit_cast(bf16x8, (u32x4){r46[0], r57[0], r46[1], r57[1]});

        o0 = mfma32(pa0, v00, o0);
        o1 = mfma32(pa0, v01, o1);
        o0 = mfma32(pa1, v10, o0);
        o1 = mfma32(pa1, v11, o1);
    };

    STAGE(0, 0);
    __syncthreads();  // drain prologue stage
    for (int c = 0; c <= cmax; c++) {
        int b = c & 1;
        if (c < cmax) STAGE(c + 1, b ^ 1);   // issue next chunk before compute
        if (c < S) COMPUTE(b, false);
        else if (c == S) COMPUTE(b, true);
        __syncthreads();  // drains staging (vmcnt0) after compute; buffer swap safe
    }

    // direct write: each wave owns its strip completely
    float inv = 1.0f / ls;
    int b_ = bh >> 4, h = bh & 15;
#pragma unroll
    for (int r = 0; r < 16; r++) {
        int crow = (r & 3) + 8 * (r >> 2) + 4 * hi;
        float ibc = __shfl(inv, crow);  // lane crow holds inv for row q0+crow
        size_t base = ((size_t)(b_ * 2048 + q0 + crow)) * 1024 + h * 64;
        Ob[base + ql] = (__bf16)(o0[r] * ibc);
        Ob[base + 32 + ql] = (__bf16)(o1[r] * ibc);
    }
}

// ---------------------------------------------------------------------------
// launch
// ---------------------------------------------------------------------------
extern "C" void kernel_launch(void* const* d_in, const int* in_sizes, int n_in,
                              void* d_out, int out_size, void* d_ws, size_t ws_size,
                              hipStream_t stream) {
    const float* x = (const float*)d_in[0];       // (2, 2048, 1024)
    const float* w_qkv = (const float*)d_in[1];   // (1024, 3072)
    const float* w_out = (const float*)d_in[2];   // (1024, 1024)
    float* out = (float*)d_out;                   // (2, 2048, 1024)

    char* ws = (char*)d_ws;
    __bf16* xb    = (__bf16*)(ws);                        //  8 MB (4096x1024)
    __bf16* wqkvT = (__bf16*)(ws + (size_t)(8  << 20));   //  6 MB (3072x1024)
    __bf16* woutT = (__bf16*)(ws + (size_t)(14 << 20));   //  2 MB (1024x1024)
    __bf16* Qf    = (__bf16*)(ws + (size_t)(16 << 20));   //  8 MB
    __bf16* Kf    = (__bf16*)(ws + (size_t)(24 << 20));   //  8 MB
    __bf16* Vf    = (__bf16*)(ws + (size_t)(32 << 20));   //  8 MB
    __bf16* Ob    = (__bf16*)(ws + (size_t)(40 << 20));   //  8 MB (4096x1024)

    prep_all<<<8192, 256, 0, stream>>>(x, xb, w_qkv, wqkvT, w_out, woutT);
    // QKV projection (M=3072 feats, N=4096 tokens)
    gemm_bt<1><<<768, 256, 0, stream>>>(
        wqkvT, xb, 3072, 4096, 1024, nullptr, Qf, Kf, Vf);
    attn_fwd9<<<512, 256, 0, stream>>>(Qf, Kf, Vf, Ob);
    // output projection (M=1024 feats, N=4096 tokens)
    gemm_bt<0><<<256, 256, 0, stream>>>(
        woutT, Ob, 1024, 4096, 1024, out, nullptr, nullptr, nullptr);
}

// Round 11
// 103.420 us; speedup vs baseline: 1.1911x; 1.1911x over previous
//
#include <hip/hip_runtime.h>

typedef __attribute__((ext_vector_type(4))) float f32x4;
typedef __attribute__((ext_vector_type(16))) float f32x16;
typedef __attribute__((ext_vector_type(8))) __bf16 bf16x8;
typedef __attribute__((ext_vector_type(4))) __bf16 bf16x4;
typedef __attribute__((ext_vector_type(4))) unsigned u32x4;
typedef __attribute__((ext_vector_type(2))) unsigned u32x2;

static __device__ __forceinline__ f32x4 mfma16(bf16x8 a, bf16x8 b, f32x4 c) {
    return __builtin_amdgcn_mfma_f32_16x16x32_bf16(a, b, c, 0, 0, 0);
}
static __device__ __forceinline__ f32x16 mfma32(bf16x8 a, bf16x8 b, f32x16 c) {
    return __builtin_amdgcn_mfma_f32_32x32x16_bf16(a, b, c, 0, 0, 0);
}
static __device__ __forceinline__ unsigned pk_bf16(float a, float b) {
    unsigned lo = __builtin_bit_cast(unsigned short, (__bf16)a);
    unsigned hh = __builtin_bit_cast(unsigned short, (__bf16)b);
    return lo | (hh << 16);
}

// Q pre-scale: 1/sqrt(64) * log2(e)  (exp2 applied directly to S, shift-free)
#define QSCALE 0.18033688f

// ---------------------------------------------------------------------------
// 1) fused prep: x cvt -> bf16 (blocks 0..4095), w_qkv transpose
//    (4096..7167), w_out transpose (7168..8191)
// ---------------------------------------------------------------------------
__global__ __launch_bounds__(256) void prep_all(const float* __restrict__ x,
                                                __bf16* __restrict__ xb,
                                                const float* __restrict__ wq,
                                                __bf16* __restrict__ wqT,
                                                const float* __restrict__ wo,
                                                __bf16* __restrict__ woT) {
    __shared__ float t[32][33];
    int bid = blockIdx.x, tid = threadIdx.x;
    if (bid < 4096) {
        int i = bid * 256 + tid;
        f32x4 v = ((const f32x4*)x)[i];
        bf16x4 o;
#pragma unroll
        for (int j = 0; j < 4; j++) o[j] = (__bf16)v[j];
        ((bf16x4*)xb)[i] = o;
        return;
    }
    const float* in;
    __bf16* out;
    int R, C, bx, by;
    if (bid < 4096 + 3072) {
        int b2 = bid - 4096;
        in = wq; out = wqT; R = 1024; C = 3072;
        bx = (b2 % 96) * 32; by = (b2 / 96) * 32;
    } else {
        int b2 = bid - 7168;
        in = wo; out = woT; R = 1024; C = 1024;
        bx = (b2 % 32) * 32; by = (b2 / 32) * 32;
    }
    int tx = tid & 31, ty = tid >> 5;  // 32 x 8
#pragma unroll
    for (int k = 0; k < 32; k += 8)
        t[ty + k][tx] = in[(size_t)(by + ty + k) * C + bx + tx];
    __syncthreads();
#pragma unroll
    for (int k = 0; k < 32; k += 8)
        out[(size_t)(bx + ty + k) * R + by + tx] = (__bf16)t[tx][ty + k];
}

// ---------------------------------------------------------------------------
// 3) bf16 GEMM (round-5 proven): orientation-B, 128x128 tile, BK=64, 4 waves,
//    single-buffer 2-barrier K-loop. MODE 0: fp32 float4 stores.
//    MODE 1: scatter QKV fragments (Q scaled; Qf/Kf bf16x4, Vf scalar).
// ---------------------------------------------------------------------------
#define BM 128
#define BN 128
#define BKG 64

template <int MODE>
__global__ __launch_bounds__(256) void gemm_bt(const __bf16* __restrict__ A,
                                               const __bf16* __restrict__ Bt,
                                               int M, int N, int K,
                                               float* __restrict__ Cout,
                                               __bf16* __restrict__ Qf,
                                               __bf16* __restrict__ Kf,
                                               __bf16* __restrict__ Vf) {
    __shared__ __attribute__((aligned(16))) __bf16 As[BM * BKG];
    __shared__ __attribute__((aligned(16))) __bf16 Bs[BN * BKG];
    int tid = threadIdx.x;
    int wave = tid >> 6, lane = tid & 63;
    int lrow = lane & 15, lgrp = lane >> 4;
    int chunk = gridDim.x >> 3;
    int bid = blockIdx.x;
    int swz = (bid & 7) * chunk + (bid >> 3);
    int nbx = N >> 7;
    int m0 = (swz / nbx) * BM, n0 = (swz % nbx) * BN;
    int wm = (wave >> 1) * 64, wn = (wave & 1) * 64;

    f32x4 acc[4][4];
#pragma unroll
    for (int i = 0; i < 4; i++)
#pragma unroll
        for (int j = 0; j < 4; j++) acc[i][j] = (f32x4){0.f, 0.f, 0.f, 0.f};

    int srow = tid >> 3;
    int gch = (tid & 7) ^ (srow & 7);
    const __bf16* aSrc = A + (size_t)(m0 + srow) * K + gch * 8;
    const __bf16* bSrc = Bt + (size_t)(n0 + srow) * K + gch * 8;

    for (int k0 = 0; k0 < K; k0 += BKG) {
#pragma unroll
        for (int c = 0; c < 4; c++) {
            __builtin_amdgcn_global_load_lds(
                (const __attribute__((address_space(1))) void*)(aSrc + k0 + (size_t)c * 32 * K),
                (__attribute__((address_space(3))) void*)(As + (c * 256 + wave * 64) * 8),
                16, 0, 0);
        }
#pragma unroll
        for (int c = 0; c < 4; c++) {
            __builtin_amdgcn_global_load_lds(
                (const __attribute__((address_space(1))) void*)(bSrc + k0 + (size_t)c * 32 * K),
                (__attribute__((address_space(3))) void*)(Bs + (c * 256 + wave * 64) * 8),
                16, 0, 0);
        }
        __syncthreads();
#pragma unroll
        for (int kk = 0; kk < 2; kk++) {
            bf16x8 af[4], bfr[4];
#pragma unroll
            for (int mt = 0; mt < 4; mt++) {
                int row = wm + mt * 16 + lrow;
                int slot = row * 8 + ((4 * kk + lgrp) ^ (row & 7));
                af[mt] = *(const bf16x8*)(As + slot * 8);
            }
#pragma unroll
            for (int nt = 0; nt < 4; nt++) {
                int row = wn + nt * 16 + lrow;
                int slot = row * 8 + ((4 * kk + lgrp) ^ (row & 7));
                bfr[nt] = *(const bf16x8*)(Bs + slot * 8);
            }
#pragma unroll
            for (int mt = 0; mt < 4; mt++)
#pragma unroll
                for (int nt = 0; nt < 4; nt++)
                    acc[mt][nt] = mfma16(af[mt], bfr[nt], acc[mt][nt]);
        }
        __syncthreads();
    }

#pragma unroll
    for (int mt = 0; mt < 4; mt++) {
#pragma unroll
        for (int nt = 0; nt < 4; nt++) {
            int f0 = m0 + wm + mt * 16 + lgrp * 4;
            int t = n0 + wn + nt * 16 + lrow;
            if (MODE == 0) {
                *(f32x4*)(Cout + (size_t)t * M + f0) = acc[mt][nt];
            } else {
                int which = f0 >> 10, hn = f0 & 1023;
                int h = hn >> 6, d0 = hn & 63;
                int b = t >> 11, li = t & 2047;
                int bh = b * 16 + h, c = li >> 5, tl = li & 31;
                size_t bhbase = (size_t)bh * 131072;
                if (which == 2) {
                    int ks = tl >> 4, hv = (tl >> 3) & 1, jv = tl & 7;
                    size_t base =
                        bhbase + ((size_t)(c * 4 + ks * 2 + hv) * 64 + d0) * 8 + jv;
#pragma unroll
                    for (int r = 0; r < 4; r++)
                        Vf[base + (size_t)r * 8] = (__bf16)acc[mt][nt][r];
                } else {
                    int st = d0 >> 4, hv = (d0 >> 3) & 1, j0 = d0 & 7;
                    size_t idx =
                        bhbase + ((size_t)(c * 8 + st * 2 + hv) * 32 + tl) * 8 + j0;
                    bf16x4 pv;
                    if (which == 0) {
#pragma unroll
                        for (int r = 0; r < 4; r++)
                            pv[r] = (__bf16)(acc[mt][nt][r] * QSCALE);
                        *(bf16x4*)(Qf + idx) = pv;
                    } else {
#pragma unroll
                        for (int r = 0; r < 4; r++) pv[r] = (__bf16)acc[mt][nt][r];
                        *(bf16x4*)(Kf + idx) = pv;
                    }
                }
            }
        }
    }
}

// ---------------------------------------------------------------------------
// 4) Causal flash attention v10: v5 structure (proven 43us) + MFMA row-sum.
//    ls is accumulated by mfma32(pa, ONES, lsacc) on the idle matrix pipe:
//    removes 16 psum adds + 2 permlane/add per chunk AND the final shfl
//    (lsacc[r] has identical row layout to o0/o1[r]).
//    2048 blocks, 4 waves split chunks (c = wave mod 4), single-barrier
//    combine (slab now carries 48 floats: o0,o1,lsacc).
// ---------------------------------------------------------------------------
template <bool MASKED>
static __device__ __forceinline__ void attn_chunk(
    int c, int ql, int hi, const __bf16* __restrict__ Kp,
    const __bf16* __restrict__ Vp, const bf16x8 (&qf)[4], bf16x8 ones,
    f32x16& o0, f32x16& o1, f32x16& lsa) {
    const __bf16* kb = Kp + ((size_t)c * 8 + hi) * 256 + ql * 8;
    bf16x8 kf[4];
#pragma unroll
    for (int st = 0; st < 4; st++) kf[st] = *(const bf16x8*)(kb + st * 512);
    const __bf16* vb = Vp + ((size_t)c * 4 + hi) * 512 + ql * 8;
    bf16x8 v00 = *(const bf16x8*)(vb);
    bf16x8 v01 = *(const bf16x8*)(vb + 256);
    bf16x8 v10 = *(const bf16x8*)(vb + 1024);
    bf16x8 v11 = *(const bf16x8*)(vb + 1280);

    f32x16 sa;
#pragma unroll
    for (int r = 0; r < 16; r++) sa[r] = 0.f;
#pragma unroll
    for (int st = 0; st < 4; st++) sa = mfma32(kf[st], qf[st], sa);

    float p[16];
#pragma unroll
    for (int r = 0; r < 16; r++) {
        float s = sa[r];
        if (MASKED) {
            int krel = (r & 3) + 8 * (r >> 2) + 4 * hi;
            if (krel > ql) s = -1e30f;
        }
        p[r] = __builtin_amdgcn_exp2f(s);
    }

    unsigned w[8];
#pragma unroll
    for (int i = 0; i < 8; i++) w[i] = pk_bf16(p[2 * i], p[2 * i + 1]);
    u32x2 r02 = __builtin_amdgcn_permlane32_swap(w[0], w[2], false, false);
    u32x2 r13 = __builtin_amdgcn_permlane32_swap(w[1], w[3], false, false);
    u32x2 r46 = __builtin_amdgcn_permlane32_swap(w[4], w[6], false, false);
    u32x2 r57 = __builtin_amdgcn_permlane32_swap(w[5], w[7], false, false);
    bf16x8 pa0 = __builtin_bit_cast(bf16x8, (u32x4){r02[0], r13[0], r02[1], r13[1]});
    bf16x8 pa1 = __builtin_bit_cast(bf16x8, (u32x4){r46[0], r57[0], r46[1], r57[1]});

    o0 = mfma32(pa0, v00, o0);
    o1 = mfma32(pa0, v01, o1);
    lsa = mfma32(pa0, ones, lsa);
    o0 = mfma32(pa1, v10, o0);
    o1 = mfma32(pa1, v11, o1);
    lsa = mfma32(pa1, ones, lsa);
}

__global__ __launch_bounds__(256, 4) void attn_fwd10(const __bf16* __restrict__ Qf,
                                                     const __bf16* __restrict__ Kf,
                                                     const __bf16* __restrict__ Vf,
                                                     __bf16* __restrict__ Ob) {
    __shared__ float comb[3][64][49];
    int tid = threadIdx.x;
    int wave = tid >> 6, lane = tid & 63;
    int ql = lane & 31, hi = lane >> 5;
    // XCD swizzle: 2048 blocks = 8 xcd x 4 heads x 64 strips (heavy first)
    int bid = blockIdx.x;
    int xcd = bid & 7, idx = bid >> 3;
    int bh = xcd * 4 + (idx >> 6);
    int strip = 63 - (idx & 63);
    int q0 = strip * 32;

    const __bf16* Qp = Qf + (size_t)bh * 131072;
    const __bf16* Kp = Kf + (size_t)bh * 131072;
    const __bf16* Vp = Vf + (size_t)bh * 131072;

    const __bf16* qb = Qp + ((size_t)strip * 8 + hi) * 256 + ql * 8;
    bf16x8 qf[4];
#pragma unroll
    for (int st = 0; st < 4; st++) qf[st] = *(const bf16x8*)(qb + st * 512);

    bf16x8 ones;
#pragma unroll
    for (int j = 0; j < 8; j++) ones[j] = (__bf16)1.0f;

    f32x16 o0, o1, lsa;
#pragma unroll
    for (int r = 0; r < 16; r++) { o0[r] = 0.f; o1[r] = 0.f; lsa[r] = 0.f; }

    for (int c = wave; c < strip; c += 4)
        attn_chunk<false>(c, ql, hi, Kp, Vp, qf, ones, o0, o1, lsa);
    if ((strip & 3) == wave)
        attn_chunk<true>(strip, ql, hi, Kp, Vp, qf, ones, o0, o1, lsa);

    // ---- combine partials: waves 1..3 -> slabs, single barrier, wave 0 sums
    if (wave >= 1) {
        float* sl = &comb[wave - 1][lane][0];
#pragma unroll
        for (int r = 0; r < 16; r++) {
            sl[r] = o0[r]; sl[16 + r] = o1[r]; sl[32 + r] = lsa[r];
        }
    }
    __syncthreads();
    if (wave == 0) {
#pragma unroll
        for (int s = 0; s < 3; s++) {
            const float* sl = &comb[s][lane][0];
#pragma unroll
            for (int r = 0; r < 16; r++) {
                o0[r] += sl[r]; o1[r] += sl[16 + r]; lsa[r] += sl[32 + r];
            }
        }
        int b = bh >> 4, h = bh & 15;
#pragma unroll
        for (int r = 0; r < 16; r++) {
            int crow = (r & 3) + 8 * (r >> 2) + 4 * hi;
            float inv;
            asm("v_rcp_f32 %0, %1" : "=v"(inv) : "v"(lsa[r]));
            size_t base = ((size_t)(b * 2048 + q0 + crow)) * 1024 + h * 64;
            Ob[base + ql] = (__bf16)(o0[r] * inv);
            Ob[base + 32 + ql] = (__bf16)(o1[r] * inv);
        }
    }
}

// ---------------------------------------------------------------------------
// launch
// ---------------------------------------------------------------------------
extern "C" void kernel_launch(void* const* d_in, const int* in_sizes, int n_in,
                              void* d_out, int out_size, void* d_ws, size_t ws_size,
                              hipStream_t stream) {
    const float* x = (const float*)d_in[0];       // (2, 2048, 1024)
    const float* w_qkv = (const float*)d_in[1];   // (1024, 3072)
    const float* w_out = (const float*)d_in[2];   // (1024, 1024)
    float* out = (float*)d_out;                   // (2, 2048, 1024)

    char* ws = (char*)d_ws;
    __bf16* xb    = (__bf16*)(ws);                        //  8 MB (4096x1024)
    __bf16* wqkvT = (__bf16*)(ws + (size_t)(8  << 20));   //  6 MB (3072x1024)
    __bf16* woutT = (__bf16*)(ws + (size_t)(14 << 20));   //  2 MB (1024x1024)
    __bf16* Qf    = (__bf16*)(ws + (size_t)(16 << 20));   //  8 MB
    __bf16* Kf    = (__bf16*)(ws + (size_t)(24 << 20));   //  8 MB
    __bf16* Vf    = (__bf16*)(ws + (size_t)(32 << 20));   //  8 MB
    __bf16* Ob    = (__bf16*)(ws + (size_t)(40 << 20));   //  8 MB (4096x1024)

    prep_all<<<8192, 256, 0, stream>>>(x, xb, w_qkv, wqkvT, w_out, woutT);
    // QKV projection (M=3072 feats, N=4096 tokens)
    gemm_bt<1><<<768, 256, 0, stream>>>(
        wqkvT, xb, 3072, 4096, 1024, nullptr, Qf, Kf, Vf);
    attn_fwd10<<<2048, 256, 0, stream>>>(Qf, Kf, Vf, Ob);
    // output projection (M=1024 feats, N=4096 tokens)
    gemm_bt<0><<<256, 256, 0, stream>>>(
        woutT, Ob, 1024, 4096, 1024, out, nullptr, nullptr, nullptr);
}

// Round 12
// 97.128 us; speedup vs baseline: 1.2683x; 1.0648x over previous
//
#include <hip/hip_runtime.h>

typedef __attribute__((ext_vector_type(4))) float f32x4;
typedef __attribute__((ext_vector_type(16))) float f32x16;
typedef __attribute__((ext_vector_type(8))) __bf16 bf16x8;
typedef __attribute__((ext_vector_type(4))) __bf16 bf16x4;
typedef __attribute__((ext_vector_type(4))) unsigned u32x4;
typedef __attribute__((ext_vector_type(2))) unsigned u32x2;

static __device__ __forceinline__ f32x4 mfma16(bf16x8 a, bf16x8 b, f32x4 c) {
    return __builtin_amdgcn_mfma_f32_16x16x32_bf16(a, b, c, 0, 0, 0);
}
static __device__ __forceinline__ f32x16 mfma32(bf16x8 a, bf16x8 b, f32x16 c) {
    return __builtin_amdgcn_mfma_f32_32x32x16_bf16(a, b, c, 0, 0, 0);
}
static __device__ __forceinline__ unsigned pk_bf16(float a, float b) {
    unsigned lo = __builtin_bit_cast(unsigned short, (__bf16)a);
    unsigned hh = __builtin_bit_cast(unsigned short, (__bf16)b);
    return lo | (hh << 16);
}

// Q pre-scale: 1/sqrt(64) * log2(e)  (exp2 applied directly to S, shift-free)
#define QSCALE 0.18033688f

// ---------------------------------------------------------------------------
// 1) fused prep: x cvt -> bf16 (blocks 0..4095), w_qkv transpose
//    (4096..7167), w_out transpose (7168..8191)
// ---------------------------------------------------------------------------
__global__ __launch_bounds__(256) void prep_all(const float* __restrict__ x,
                                                __bf16* __restrict__ xb,
                                                const float* __restrict__ wq,
                                                __bf16* __restrict__ wqT,
                                                const float* __restrict__ wo,
                                                __bf16* __restrict__ woT) {
    __shared__ float t[32][33];
    int bid = blockIdx.x, tid = threadIdx.x;
    if (bid < 4096) {
        int i = bid * 256 + tid;
        f32x4 v = ((const f32x4*)x)[i];
        bf16x4 o;
#pragma unroll
        for (int j = 0; j < 4; j++) o[j] = (__bf16)v[j];
        ((bf16x4*)xb)[i] = o;
        return;
    }
    const float* in;
    __bf16* out;
    int R, C, bx, by;
    if (bid < 4096 + 3072) {
        int b2 = bid - 4096;
        in = wq; out = wqT; R = 1024; C = 3072;
        bx = (b2 % 96) * 32; by = (b2 / 96) * 32;
    } else {
        int b2 = bid - 7168;
        in = wo; out = woT; R = 1024; C = 1024;
        bx = (b2 % 32) * 32; by = (b2 / 32) * 32;
    }
    int tx = tid & 31, ty = tid >> 5;  // 32 x 8
#pragma unroll
    for (int k = 0; k < 32; k += 8)
        t[ty + k][tx] = in[(size_t)(by + ty + k) * C + bx + tx];
    __syncthreads();
#pragma unroll
    for (int k = 0; k < 32; k += 8)
        out[(size_t)(bx + ty + k) * R + by + tx] = (__bf16)t[tx][ty + k];
}

// ---------------------------------------------------------------------------
// 3) bf16 GEMM (proven 2-barrier structure), orientation-B, BMv x 128 tile,
//    BK=64, 4 waves. MODE 0: fp32 float4 stores (out projection, BMv=64 ->
//    512 blocks, 6 blocks/CU for inter-block overlap).
//    MODE 1: scatter QKV fragments (BMv=128); per-XCD 2D rectangle swizzle
//    (12M x 8N tiles -> ~5MB L2 footprint instead of 8.75MB B-stream).
// ---------------------------------------------------------------------------
#define BN 128
#define BKG 64

template <int MODE, int BMv>
__global__ __launch_bounds__(256) void gemm_bt(const __bf16* __restrict__ A,
                                               const __bf16* __restrict__ Bt,
                                               int M, int N, int K,
                                               float* __restrict__ Cout,
                                               __bf16* __restrict__ Qf,
                                               __bf16* __restrict__ Kf,
                                               __bf16* __restrict__ Vf) {
    constexpr int nMt = BMv / 32;  // 16-row tiles per wave quadrant
    __shared__ __attribute__((aligned(16))) __bf16 As[BMv * BKG];
    __shared__ __attribute__((aligned(16))) __bf16 Bs[BN * BKG];
    int tid = threadIdx.x;
    int wave = tid >> 6, lane = tid & 63;
    int lrow = lane & 15, lgrp = lane >> 4;
    int bid = blockIdx.x;
    int m0, n0;
    if (MODE == 1) {
        // 768 blocks: XCD (bid&7) owns a 12M x 8N rectangle of 128-tiles
        int x = bid & 7, j = bid >> 3;  // j in 0..95
        int mx = x & 1, nx = x >> 1;    // 2 x 4 XCD grid
        int mi = j >> 3, ni = j & 7;    // 12 x 8 within rectangle
        m0 = (mx * 12 + mi) * BMv;
        n0 = (nx * 8 + ni) * BN;
    } else {
        int chunk = gridDim.x >> 3;
        int swz = (bid & 7) * chunk + (bid >> 3);
        int nbx = N >> 7;
        m0 = (swz / nbx) * BMv;
        n0 = (swz % nbx) * BN;
    }
    int wm = (wave >> 1) * (BMv / 2);
    int wn = (wave & 1) * 64;

    f32x4 acc[nMt][4];
#pragma unroll
    for (int i = 0; i < nMt; i++)
#pragma unroll
        for (int j = 0; j < 4; j++) acc[i][j] = (f32x4){0.f, 0.f, 0.f, 0.f};

    int srow = tid >> 3;
    int gch = (tid & 7) ^ (srow & 7);
    const __bf16* aSrc = A + (size_t)(m0 + srow) * K + gch * 8;
    const __bf16* bSrc = Bt + (size_t)(n0 + srow) * K + gch * 8;

    for (int k0 = 0; k0 < K; k0 += BKG) {
#pragma unroll
        for (int c = 0; c < BMv / 32; c++) {
            __builtin_amdgcn_global_load_lds(
                (const __attribute__((address_space(1))) void*)(aSrc + k0 + (size_t)c * 32 * K),
                (__attribute__((address_space(3))) void*)(As + (c * 256 + wave * 64) * 8),
                16, 0, 0);
        }
#pragma unroll
        for (int c = 0; c < 4; c++) {
            __builtin_amdgcn_global_load_lds(
                (const __attribute__((address_space(1))) void*)(bSrc + k0 + (size_t)c * 32 * K),
                (__attribute__((address_space(3))) void*)(Bs + (c * 256 + wave * 64) * 8),
                16, 0, 0);
        }
        __syncthreads();
#pragma unroll
        for (int kk = 0; kk < 2; kk++) {
            bf16x8 af[nMt], bfr[4];
#pragma unroll
            for (int mt = 0; mt < nMt; mt++) {
                int row = wm + mt * 16 + lrow;
                int slot = row * 8 + ((4 * kk + lgrp) ^ (row & 7));
                af[mt] = *(const bf16x8*)(As + slot * 8);
            }
#pragma unroll
            for (int nt = 0; nt < 4; nt++) {
                int row = wn + nt * 16 + lrow;
                int slot = row * 8 + ((4 * kk + lgrp) ^ (row & 7));
                bfr[nt] = *(const bf16x8*)(Bs + slot * 8);
            }
#pragma unroll
            for (int mt = 0; mt < nMt; mt++)
#pragma unroll
                for (int nt = 0; nt < 4; nt++)
                    acc[mt][nt] = mfma16(af[mt], bfr[nt], acc[mt][nt]);
        }
        __syncthreads();
    }

#pragma unroll
    for (int mt = 0; mt < nMt; mt++) {
#pragma unroll
        for (int nt = 0; nt < 4; nt++) {
            int f0 = m0 + wm + mt * 16 + lgrp * 4;
            int t = n0 + wn + nt * 16 + lrow;
            if (MODE == 0) {
                *(f32x4*)(Cout + (size_t)t * M + f0) = acc[mt][nt];
            } else {
                int which = f0 >> 10, hn = f0 & 1023;
                int h = hn >> 6, d0 = hn & 63;
                int b = t >> 11, li = t & 2047;
                int bh = b * 16 + h, c = li >> 5, tl = li & 31;
                size_t bhbase = (size_t)bh * 131072;
                if (which == 2) {
                    int ks = tl >> 4, hv = (tl >> 3) & 1, jv = tl & 7;
                    size_t base =
                        bhbase + ((size_t)(c * 4 + ks * 2 + hv) * 64 + d0) * 8 + jv;
#pragma unroll
                    for (int r = 0; r < 4; r++)
                        Vf[base + (size_t)r * 8] = (__bf16)acc[mt][nt][r];
                } else {
                    int st = d0 >> 4, hv = (d0 >> 3) & 1, j0 = d0 & 7;
                    size_t idx =
                        bhbase + ((size_t)(c * 8 + st * 2 + hv) * 32 + tl) * 8 + j0;
                    bf16x4 pv;
                    if (which == 0) {
#pragma unroll
                        for (int r = 0; r < 4; r++)
                            pv[r] = (__bf16)(acc[mt][nt][r] * QSCALE);
                        *(bf16x4*)(Qf + idx) = pv;
                    } else {
#pragma unroll
                        for (int r = 0; r < 4; r++) pv[r] = (__bf16)acc[mt][nt][r];
                        *(bf16x4*)(Kf + idx) = pv;
                    }
                }
            }
        }
    }
}

// ---------------------------------------------------------------------------
// 4) Causal flash attention v10 (proven): swapped-QK^T, 32x32x16 MFMA,
//    fragment-swizzled Q/K/V, MFMA row-sum via ones-operand (lsacc shares
//    o0/o1 row layout). 2048 blocks, 4 waves split chunks, single-barrier
//    combine (48-float slabs).
// ---------------------------------------------------------------------------
template <bool MASKED>
static __device__ __forceinline__ void attn_chunk(
    int c, int ql, int hi, const __bf16* __restrict__ Kp,
    const __bf16* __restrict__ Vp, const bf16x8 (&qf)[4], bf16x8 ones,
    f32x16& o0, f32x16& o1, f32x16& lsa) {
    const __bf16* kb = Kp + ((size_t)c * 8 + hi) * 256 + ql * 8;
    bf16x8 kf[4];
#pragma unroll
    for (int st = 0; st < 4; st++) kf[st] = *(const bf16x8*)(kb + st * 512);
    const __bf16* vb = Vp + ((size_t)c * 4 + hi) * 512 + ql * 8;
    bf16x8 v00 = *(const bf16x8*)(vb);
    bf16x8 v01 = *(const bf16x8*)(vb + 256);
    bf16x8 v10 = *(const bf16x8*)(vb + 1024);
    bf16x8 v11 = *(const bf16x8*)(vb + 1280);

    f32x16 sa;
#pragma unroll
    for (int r = 0; r < 16; r++) sa[r] = 0.f;
#pragma unroll
    for (int st = 0; st < 4; st++) sa = mfma32(kf[st], qf[st], sa);

    float p[16];
#pragma unroll
    for (int r = 0; r < 16; r++) {
        float s = sa[r];
        if (MASKED) {
            int krel = (r & 3) + 8 * (r >> 2) + 4 * hi;
            if (krel > ql) s = -1e30f;
        }
        p[r] = __builtin_amdgcn_exp2f(s);
    }

    unsigned w[8];
#pragma unroll
    for (int i = 0; i < 8; i++) w[i] = pk_bf16(p[2 * i], p[2 * i + 1]);
    u32x2 r02 = __builtin_amdgcn_permlane32_swap(w[0], w[2], false, false);
    u32x2 r13 = __builtin_amdgcn_permlane32_swap(w[1], w[3], false, false);
    u32x2 r46 = __builtin_amdgcn_permlane32_swap(w[4], w[6], false, false);
    u32x2 r57 = __builtin_amdgcn_permlane32_swap(w[5], w[7], false, false);
    bf16x8 pa0 = __builtin_bit_cast(bf16x8, (u32x4){r02[0], r13[0], r02[1], r13[1]});
    bf16x8 pa1 = __builtin_bit_cast(bf16x8, (u32x4){r46[0], r57[0], r46[1], r57[1]});

    o0 = mfma32(pa0, v00, o0);
    o1 = mfma32(pa0, v01, o1);
    lsa = mfma32(pa0, ones, lsa);
    o0 = mfma32(pa1, v10, o0);
    o1 = mfma32(pa1, v11, o1);
    lsa = mfma32(pa1, ones, lsa);
}

__global__ __launch_bounds__(256, 4) void attn_fwd10(const __bf16* __restrict__ Qf,
                                                     const __bf16* __restrict__ Kf,
                                                     const __bf16* __restrict__ Vf,
                                                     __bf16* __restrict__ Ob) {
    __shared__ float comb[3][64][49];
    int tid = threadIdx.x;
    int wave = tid >> 6, lane = tid & 63;
    int ql = lane & 31, hi = lane >> 5;
    // XCD swizzle: 2048 blocks = 8 xcd x 4 heads x 64 strips (heavy first)
    int bid = blockIdx.x;
    int xcd = bid & 7, idx = bid >> 3;
    int bh = xcd * 4 + (idx >> 6);
    int strip = 63 - (idx & 63);
    int q0 = strip * 32;

    const __bf16* Qp = Qf + (size_t)bh * 131072;
    const __bf16* Kp = Kf + (size_t)bh * 131072;
    const __bf16* Vp = Vf + (size_t)bh * 131072;

    const __bf16* qb = Qp + ((size_t)strip * 8 + hi) * 256 + ql * 8;
    bf16x8 qf[4];
#pragma unroll
    for (int st = 0; st < 4; st++) qf[st] = *(const bf16x8*)(qb + st * 512);

    bf16x8 ones;
#pragma unroll
    for (int j = 0; j < 8; j++) ones[j] = (__bf16)1.0f;

    f32x16 o0, o1, lsa;
#pragma unroll
    for (int r = 0; r < 16; r++) { o0[r] = 0.f; o1[r] = 0.f; lsa[r] = 0.f; }

    for (int c = wave; c < strip; c += 4)
        attn_chunk<false>(c, ql, hi, Kp, Vp, qf, ones, o0, o1, lsa);
    if ((strip & 3) == wave)
        attn_chunk<true>(strip, ql, hi, Kp, Vp, qf, ones, o0, o1, lsa);

    // ---- combine partials: waves 1..3 -> slabs, single barrier, wave 0 sums
    if (wave >= 1) {
        float* sl = &comb[wave - 1][lane][0];
#pragma unroll
        for (int r = 0; r < 16; r++) {
            sl[r] = o0[r]; sl[16 + r] = o1[r]; sl[32 + r] = lsa[r];
        }
    }
    __syncthreads();
    if (wave == 0) {
#pragma unroll
        for (int s = 0; s < 3; s++) {
            const float* sl = &comb[s][lane][0];
#pragma unroll
            for (int r = 0; r < 16; r++) {
                o0[r] += sl[r]; o1[r] += sl[16 + r]; lsa[r] += sl[32 + r];
            }
        }
        int b = bh >> 4, h = bh & 15;
#pragma unroll
        for (int r = 0; r < 16; r++) {
            int crow = (r & 3) + 8 * (r >> 2) + 4 * hi;
            float inv;
            asm("v_rcp_f32 %0, %1" : "=v"(inv) : "v"(lsa[r]));
            size_t base = ((size_t)(b * 2048 + q0 + crow)) * 1024 + h * 64;
            Ob[base + ql] = (__bf16)(o0[r] * inv);
            Ob[base + 32 + ql] = (__bf16)(o1[r] * inv);
        }
    }
}

// ---------------------------------------------------------------------------
// launch
// ---------------------------------------------------------------------------
extern "C" void kernel_launch(void* const* d_in, const int* in_sizes, int n_in,
                              void* d_out, int out_size, void* d_ws, size_t ws_size,
                              hipStream_t stream) {
    const float* x = (const float*)d_in[0];       // (2, 2048, 1024)
    const float* w_qkv = (const float*)d_in[1];   // (1024, 3072)
    const float* w_out = (const float*)d_in[2];   // (1024, 1024)
    float* out = (float*)d_out;                   // (2, 2048, 1024)

    char* ws = (char*)d_ws;
    __bf16* xb    = (__bf16*)(ws);                        //  8 MB (4096x1024)
    __bf16* wqkvT = (__bf16*)(ws + (size_t)(8  << 20));   //  6 MB (3072x1024)
    __bf16* woutT = (__bf16*)(ws + (size_t)(14 << 20));   //  2 MB (1024x1024)
    __bf16* Qf    = (__bf16*)(ws + (size_t)(16 << 20));   //  8 MB
    __bf16* Kf    = (__bf16*)(ws + (size_t)(24 << 20));   //  8 MB
    __bf16* Vf    = (__bf16*)(ws + (size_t)(32 << 20));   //  8 MB
    __bf16* Ob    = (__bf16*)(ws + (size_t)(40 << 20));   //  8 MB (4096x1024)

    prep_all<<<8192, 256, 0, stream>>>(x, xb, w_qkv, wqkvT, w_out, woutT);
    // QKV projection (M=3072 feats, N=4096 tokens), 2D-rect XCD swizzle
    gemm_bt<1, 128><<<768, 256, 0, stream>>>(
        wqkvT, xb, 3072, 4096, 1024, nullptr, Qf, Kf, Vf);
    attn_fwd10<<<2048, 256, 0, stream>>>(Qf, Kf, Vf, Ob);
    // output projection (M=1024 feats, N=4096 tokens), BM=64 -> 512 blocks
    gemm_bt<0, 64><<<512, 256, 0, stream>>>(
        woutT, Ob, 1024, 4096, 1024, out, nullptr, nullptr, nullptr);
}